// Round 2
// baseline (1191.329 us; speedup 1.0000x reference)
//
#include <hip/hip_runtime.h>
#include <hip/hip_bf16.h>

#define B 4
#define S 2048
#define H 16
#define D 64
#define HID 1024

typedef __hip_bfloat16 bf16;

static __device__ __forceinline__ float b2f(bf16 v) { return __bfloat162float(v); }

// ---------------------------------------------------------------------------
// Kernel 0a: dtype detector. Block i samples input i read as bf16; true-bf16
// data (N(0,1) or uniform ±0.125) can never have |v|>1e4 or NaN; fp32 data
// read as bf16 has ~45% wild low-halves. flags[i]=1 -> buffer is fp32.
// ---------------------------------------------------------------------------
__global__ __launch_bounds__(256) void detect_kernel(
    const void* p0, const void* p1, const void* p2, const void* p3,
    const void* p4, const void* p5, const void* p6, const void* p7,
    const void* p8, int* flags)
{
    __shared__ int cnt;
    const void* ps[9] = {p0, p1, p2, p3, p4, p5, p6, p7, p8};
    const int   ns[9] = {B * S * D, D * HID, HID, D * HID, HID,
                         D * HID, HID, HID * D, D};
    const int i = blockIdx.x;
    const bf16* p = (const bf16*)ps[i];
    int n = ns[i];
    if (n > 2048) n = 2048;
    if (threadIdx.x == 0) cnt = 0;
    __syncthreads();
    int wild = 0;
    for (int t = threadIdx.x; t < n; t += 256) {
        float f = b2f(p[t]);
        if (!(f == f) || fabsf(f) > 1e4f) wild++;
    }
    if (wild) atomicAdd(&cnt, wild);
    __syncthreads();
    if (threadIdx.x == 0) flags[i] = (cnt >= 2) ? 1 : 0;
}

// ---------------------------------------------------------------------------
// Kernel 0b: stage input `which` as fp32 into ws (per detected dtype).
// ---------------------------------------------------------------------------
__global__ __launch_bounds__(256) void convert_kernel(
    const void* __restrict__ src, float* __restrict__ dst, int n,
    const int* __restrict__ flags, int which)
{
    const int idx = blockIdx.x * 256 + threadIdx.x;
    if (idx >= n) return;
    if (flags[which]) dst[idx] = ((const float*)src)[idx];
    else              dst[idx] = b2f(((const bf16*)src)[idx]);
}

// ---------------------------------------------------------------------------
// Kernel 1: fused QKV projection (fp32 staged inputs).
// x:[B*S, 64] @ W{q,k,v}:[64,1024] + b -> Q,K,V stored [B][H][S][D] (bf16).
// ---------------------------------------------------------------------------
__global__ __launch_bounds__(256) void qkv_proj_kernel(
    const float* __restrict__ x,
    const float* __restrict__ Wq, const float* __restrict__ bq,
    const float* __restrict__ Wk, const float* __restrict__ bk,
    const float* __restrict__ Wv, const float* __restrict__ bv,
    bf16* __restrict__ q, bf16* __restrict__ k, bf16* __restrict__ v)
{
    __shared__ float xs[4][D];
    const int tid = threadIdx.x;
    const int r0  = blockIdx.x * 4;

    {
        int rr = tid >> 6, c = tid & 63;
        xs[rr][c] = x[(size_t)(r0 + rr) * D + c];
    }
    __syncthreads();

    #pragma unroll
    for (int cblk = 0; cblk < 4; ++cblk) {
        const int n = cblk * 256 + tid;
        float aq[4] = {0.f, 0.f, 0.f, 0.f};
        float ak[4] = {0.f, 0.f, 0.f, 0.f};
        float av[4] = {0.f, 0.f, 0.f, 0.f};
        for (int d = 0; d < D; ++d) {
            float wqv = Wq[d * HID + n];
            float wkv = Wk[d * HID + n];
            float wvv = Wv[d * HID + n];
            #pragma unroll
            for (int r = 0; r < 4; ++r) {
                float xv = xs[r][d];
                aq[r] += xv * wqv;
                ak[r] += xv * wkv;
                av[r] += xv * wvv;
            }
        }
        const int h = n >> 6, dd = n & 63;
        const float bqv = bq[n], bkv = bk[n], bvv = bv[n];
        #pragma unroll
        for (int r = 0; r < 4; ++r) {
            int row = r0 + r;
            int bb = row >> 11;           // S = 2048
            int ss = row & (S - 1);
            size_t o = ((size_t)(bb * H + h) * S + ss) * D + dd;
            q[o] = __float2bfloat16(aq[r] + bqv);
            k[o] = __float2bfloat16(ak[r] + bkv);
            v[o] = __float2bfloat16(av[r] + bvv);
        }
    }
}

// ---------------------------------------------------------------------------
// Kernel 2: flash-style causal attention, fp32 vector ALU.
// Grid: (S/64 q-tiles, B*H). Block 256 threads = 16x16 (ty,tx).
// ---------------------------------------------------------------------------
#define BT  64
#define STR 68   // 64 + 4 pad: float4-aligned, <=2-way LDS conflicts (free)
#define MNEG -30000.0f

__global__ __launch_bounds__(256) void flash_kernel(
    const bf16* __restrict__ qg, const bf16* __restrict__ kg,
    const bf16* __restrict__ vg, bf16* __restrict__ og)
{
    __shared__ float Qs[BT * STR];
    __shared__ float KPs[BT * STR];  // K tile; reused to hold P
    __shared__ float Vs[BT * STR];

    const int tid = threadIdx.x;
    const int tx  = tid & 15;
    const int ty  = tid >> 4;
    const int qt  = blockIdx.x;
    const int bh  = blockIdx.y;

    const size_t hbase = (size_t)bh * S * D;

    {   // load Q tile, pre-scaled by 1/sqrt(D) = 0.125
        const uint4* gv = reinterpret_cast<const uint4*>(qg + hbase + (size_t)qt * BT * D);
        #pragma unroll
        for (int i = 0; i < 2; ++i) {
            int vi = tid + i * 256;
            int r  = vi >> 3;
            int c0 = (vi & 7) * 8;
            uint4 u = gv[vi];
            const bf16* hp = reinterpret_cast<const bf16*>(&u);
            float* dst = &Qs[r * STR + c0];
            #pragma unroll
            for (int j = 0; j < 8; ++j) dst[j] = b2f(hp[j]) * 0.125f;
        }
    }

    float O[4][4];
    float m[4], l[4];
    #pragma unroll
    for (int i = 0; i < 4; ++i) {
        m[i] = MNEG; l[i] = 0.f;
        #pragma unroll
        for (int j = 0; j < 4; ++j) O[i][j] = 0.f;
    }

    for (int kt = 0; kt <= qt; ++kt) {
        __syncthreads();   // prior PV done with KPs/Vs
        {
            const uint4* kv4 = reinterpret_cast<const uint4*>(kg + hbase + (size_t)kt * BT * D);
            const uint4* vv4 = reinterpret_cast<const uint4*>(vg + hbase + (size_t)kt * BT * D);
            #pragma unroll
            for (int i = 0; i < 2; ++i) {
                int vi = tid + i * 256;
                int r  = vi >> 3;
                int c0 = (vi & 7) * 8;
                uint4 uk = kv4[vi];
                uint4 uv = vv4[vi];
                const bf16* hk = reinterpret_cast<const bf16*>(&uk);
                const bf16* hv = reinterpret_cast<const bf16*>(&uv);
                float* dk = &KPs[r * STR + c0];
                float* dv = &Vs[r * STR + c0];
                #pragma unroll
                for (int j = 0; j < 8; ++j) { dk[j] = b2f(hk[j]); dv[j] = b2f(hv[j]); }
            }
        }
        __syncthreads();

        float sc[4][4];
        #pragma unroll
        for (int i = 0; i < 4; ++i)
            #pragma unroll
            for (int j = 0; j < 4; ++j) sc[i][j] = 0.f;

        for (int d = 0; d < D; d += 4) {
            float4 qv[4], kv[4];
            #pragma unroll
            for (int i = 0; i < 4; ++i)
                qv[i] = *reinterpret_cast<const float4*>(&Qs[(ty * 4 + i) * STR + d]);
            #pragma unroll
            for (int j = 0; j < 4; ++j)
                kv[j] = *reinterpret_cast<const float4*>(&KPs[(tx + 16 * j) * STR + d]);
            #pragma unroll
            for (int i = 0; i < 4; ++i)
                #pragma unroll
                for (int j = 0; j < 4; ++j)
                    sc[i][j] += qv[i].x * kv[j].x + qv[i].y * kv[j].y +
                                qv[i].z * kv[j].z + qv[i].w * kv[j].w;
        }

        if (kt == qt) {   // diagonal tile: mask col > row
            #pragma unroll
            for (int i = 0; i < 4; ++i)
                #pragma unroll
                for (int j = 0; j < 4; ++j)
                    if (tx + 16 * j > ty * 4 + i) sc[i][j] = MNEG;
        }

        float alpha[4];
        #pragma unroll
        for (int i = 0; i < 4; ++i) {
            float rm = fmaxf(fmaxf(sc[i][0], sc[i][1]), fmaxf(sc[i][2], sc[i][3]));
            #pragma unroll
            for (int off = 8; off > 0; off >>= 1) rm = fmaxf(rm, __shfl_xor(rm, off));
            float mn = fmaxf(m[i], rm);
            alpha[i] = __expf(m[i] - mn);
            float rs = 0.f;
            #pragma unroll
            for (int j = 0; j < 4; ++j) {
                float p = __expf(sc[i][j] - mn);
                sc[i][j] = p;
                rs += p;
            }
            #pragma unroll
            for (int off = 8; off > 0; off >>= 1) rs += __shfl_xor(rs, off);
            l[i] = l[i] * alpha[i] + rs;
            m[i] = mn;
        }

        __syncthreads();   // all lanes done reading KPs as K
        #pragma unroll
        for (int i = 0; i < 4; ++i)
            #pragma unroll
            for (int j = 0; j < 4; ++j)
                KPs[(ty * 4 + i) * STR + tx + 16 * j] = sc[i][j];
        #pragma unroll
        for (int i = 0; i < 4; ++i)
            #pragma unroll
            for (int j = 0; j < 4; ++j) O[i][j] *= alpha[i];
        __syncthreads();   // P visible

        for (int k0 = 0; k0 < BT; k0 += 4) {
            float pr[4][4];
            #pragma unroll
            for (int i = 0; i < 4; ++i) {
                float4 t = *reinterpret_cast<const float4*>(&KPs[(ty * 4 + i) * STR + k0]);
                pr[i][0] = t.x; pr[i][1] = t.y; pr[i][2] = t.z; pr[i][3] = t.w;
            }
            #pragma unroll
            for (int kk = 0; kk < 4; ++kk) {
                float4 vv = *reinterpret_cast<const float4*>(&Vs[(k0 + kk) * STR + tx * 4]);
                #pragma unroll
                for (int i = 0; i < 4; ++i) {
                    O[i][0] += pr[i][kk] * vv.x;
                    O[i][1] += pr[i][kk] * vv.y;
                    O[i][2] += pr[i][kk] * vv.z;
                    O[i][3] += pr[i][kk] * vv.w;
                }
            }
        }
    }

    const int qrow0 = qt * BT + ty * 4;
    #pragma unroll
    for (int i = 0; i < 4; ++i) {
        float inv = 1.f / l[i];
        size_t base = hbase + (size_t)(qrow0 + i) * D + tx * 4;
        #pragma unroll
        for (int j = 0; j < 4; ++j)
            og[base + j] = __float2bfloat16(O[i][j] * inv);
    }
}

// ---------------------------------------------------------------------------
// Kernel 3: output projection (fp32 staged Wo/bo); store dtype per flags[0].
// ---------------------------------------------------------------------------
__global__ __launch_bounds__(256) void out_proj_kernel(
    const bf16* __restrict__ o, const float* __restrict__ Wo,
    const float* __restrict__ bo, void* __restrict__ out,
    const int* __restrict__ flags)
{
    __shared__ float os[4][HID];
    __shared__ float red[4][4][64];   // [chunk][row][col]
    const int tid = threadIdx.x;
    const int r0  = blockIdx.x * 4;

    #pragma unroll
    for (int i = 0; i < 16; ++i) {
        int idx = tid + i * 256;      // 0..4095
        int rr  = idx >> 10;
        int kk  = idx & 1023;
        int h   = kk >> 6, d = kk & 63;
        int row = r0 + rr;
        int bb  = row >> 11;
        int ss  = row & (S - 1);
        os[rr][kk] = b2f(o[((size_t)(bb * H + h) * S + ss) * D + d]);
    }
    __syncthreads();

    const int n = tid & 63, ch = tid >> 6;
    float acc[4] = {0.f, 0.f, 0.f, 0.f};
    for (int kk = ch * 256; kk < ch * 256 + 256; ++kk) {
        float w = Wo[kk * 64 + n];
        #pragma unroll
        for (int r = 0; r < 4; ++r) acc[r] += os[r][kk] * w;
    }
    #pragma unroll
    for (int r = 0; r < 4; ++r) red[ch][r][n] = acc[r];
    __syncthreads();

    {
        int rr = tid >> 6, nn = tid & 63;
        float sum = red[0][rr][nn] + red[1][rr][nn] + red[2][rr][nn] +
                    red[3][rr][nn] + bo[nn];
        size_t oidx = (size_t)(r0 + rr) * 64 + nn;
        if (flags[0]) ((float*)out)[oidx] = sum;
        else          ((bf16*)out)[oidx]  = __float2bfloat16(sum);
    }
}

// ---------------------------------------------------------------------------
extern "C" void kernel_launch(void* const* d_in, const int* in_sizes, int n_in,
                              void* d_out, int out_size, void* d_ws, size_t ws_size,
                              hipStream_t stream)
{
    char* ws = (char*)d_ws;
    const size_t qkv_bytes = (size_t)B * S * HID * sizeof(bf16);  // 16 MiB each
    bf16* qw = (bf16*)(ws);
    bf16* kw = (bf16*)(ws + qkv_bytes);
    bf16* vw = (bf16*)(ws + 2 * qkv_bytes);
    bf16* ow = (bf16*)(ws + 3 * qkv_bytes);

    float* stage = (float*)(ws + 4 * qkv_bytes);
    float* xf  = stage;                    // 524288
    float* wqf = xf  + (size_t)B * S * D;  // 65536
    float* bqf = wqf + D * HID;            // 1024
    float* wkf = bqf + HID;
    float* bkf = wkf + D * HID;
    float* wvf = bkf + HID;
    float* bvf = wvf + D * HID;
    float* wof = bvf + HID;
    float* bof = wof + HID * D;            // 64
    int* flags = (int*)(bof + D);

    detect_kernel<<<9, 256, 0, stream>>>(d_in[0], d_in[1], d_in[2], d_in[3],
                                         d_in[4], d_in[5], d_in[6], d_in[7],
                                         d_in[8], flags);

    const int  sizes[9] = {B * S * D, D * HID, HID, D * HID, HID,
                           D * HID, HID, HID * D, D};
    float*     dsts[9]  = {xf, wqf, bqf, wkf, bkf, wvf, bvf, wof, bof};
    for (int i = 0; i < 9; ++i) {
        int blocks = (sizes[i] + 255) / 256;
        convert_kernel<<<blocks, 256, 0, stream>>>(d_in[i], dsts[i], sizes[i],
                                                   flags, i);
    }

    qkv_proj_kernel<<<dim3(B * S / 4), 256, 0, stream>>>(xf, wqf, bqf, wkf, bkf,
                                                         wvf, bvf, qw, kw, vw);
    flash_kernel<<<dim3(S / BT, B * H), 256, 0, stream>>>(qw, kw, vw, ow);
    out_proj_kernel<<<dim3(B * S / 4), 256, 0, stream>>>(ow, wof, bof, d_out, flags);
}

// Round 3
// 467.349 us; speedup vs baseline: 2.5491x; 2.5491x over previous
//
#include <hip/hip_runtime.h>
#include <hip/hip_bf16.h>

#define B 4
#define S 2048
#define H 16
#define D 64
#define HID 1024

typedef __hip_bfloat16 bf16;
typedef __attribute__((ext_vector_type(8))) short bf16x8;
typedef __attribute__((ext_vector_type(4))) float f32x4;

static __device__ __forceinline__ float b2f(bf16 v) { return __bfloat162float(v); }

// ---------------------------------------------------------------------------
// Kernel 0a: dtype detector (kept from R2 — proven). flags[i]=1 -> fp32.
// ---------------------------------------------------------------------------
__global__ __launch_bounds__(256) void detect_kernel(
    const void* p0, const void* p1, const void* p2, const void* p3,
    const void* p4, const void* p5, const void* p6, const void* p7,
    const void* p8, int* flags)
{
    __shared__ int cnt;
    const void* ps[9] = {p0, p1, p2, p3, p4, p5, p6, p7, p8};
    const int   ns[9] = {B * S * D, D * HID, HID, D * HID, HID,
                         D * HID, HID, HID * D, D};
    const int i = blockIdx.x;
    const bf16* p = (const bf16*)ps[i];
    int n = ns[i];
    if (n > 2048) n = 2048;
    if (threadIdx.x == 0) cnt = 0;
    __syncthreads();
    int wild = 0;
    for (int t = threadIdx.x; t < n; t += 256) {
        float f = b2f(p[t]);
        if (!(f == f) || fabsf(f) > 1e4f) wild++;
    }
    if (wild) atomicAdd(&cnt, wild);
    __syncthreads();
    if (threadIdx.x == 0) flags[i] = (cnt >= 2) ? 1 : 0;
}

__global__ __launch_bounds__(256) void convert_kernel(
    const void* __restrict__ src, float* __restrict__ dst, int n,
    const int* __restrict__ flags, int which)
{
    const int idx = blockIdx.x * 256 + threadIdx.x;
    if (idx >= n) return;
    if (flags[which]) dst[idx] = ((const float*)src)[idx];
    else              dst[idx] = b2f(((const bf16*)src)[idx]);
}

// ---------------------------------------------------------------------------
// Kernel 1: fused QKV projection (unchanged from R2).
// ---------------------------------------------------------------------------
__global__ __launch_bounds__(256) void qkv_proj_kernel(
    const float* __restrict__ x,
    const float* __restrict__ Wq, const float* __restrict__ bq,
    const float* __restrict__ Wk, const float* __restrict__ bk,
    const float* __restrict__ Wv, const float* __restrict__ bv,
    bf16* __restrict__ q, bf16* __restrict__ k, bf16* __restrict__ v)
{
    __shared__ float xs[4][D];
    const int tid = threadIdx.x;
    const int r0  = blockIdx.x * 4;

    {
        int rr = tid >> 6, c = tid & 63;
        xs[rr][c] = x[(size_t)(r0 + rr) * D + c];
    }
    __syncthreads();

    #pragma unroll
    for (int cblk = 0; cblk < 4; ++cblk) {
        const int n = cblk * 256 + tid;
        float aq[4] = {0.f, 0.f, 0.f, 0.f};
        float ak[4] = {0.f, 0.f, 0.f, 0.f};
        float av[4] = {0.f, 0.f, 0.f, 0.f};
        for (int d = 0; d < D; ++d) {
            float wqv = Wq[d * HID + n];
            float wkv = Wk[d * HID + n];
            float wvv = Wv[d * HID + n];
            #pragma unroll
            for (int r = 0; r < 4; ++r) {
                float xv = xs[r][d];
                aq[r] += xv * wqv;
                ak[r] += xv * wkv;
                av[r] += xv * wvv;
            }
        }
        const int h = n >> 6, dd = n & 63;
        const float bqv = bq[n], bkv = bk[n], bvv = bv[n];
        #pragma unroll
        for (int r = 0; r < 4; ++r) {
            int row = r0 + r;
            int bb = row >> 11;
            int ss = row & (S - 1);
            size_t o = ((size_t)(bb * H + h) * S + ss) * D + dd;
            q[o] = __float2bfloat16(aq[r] + bqv);
            k[o] = __float2bfloat16(ak[r] + bkv);
            v[o] = __float2bfloat16(av[r] + bvv);
        }
    }
}

// ---------------------------------------------------------------------------
// Kernel 2: flash causal attention with bf16 MFMA (16x16x32).
// Grid (S/64, B*H); 256 threads = 4 waves; each wave owns 16 q-rows.
// Layouts (m89/m91/m120-verified):
//   A-frag:  A[m=lane&15][k=quad*8+j]       (8 contiguous bf16 -> b128)
//   B-frag:  B[k=quad*8+j][n=lane&15]       (from Ks rows / Vt rows)
//   C/D:     D[row=quad*4+reg][col=lane&15]
// P round-trips through per-wave LDS (C layout -> A layout).
// LDS rows stride 72 bf16: b128 frag reads spread 8-lane groups over
// disjoint 4-bank sets (bandwidth-floor optimal).
// ---------------------------------------------------------------------------
#define BT   64
#define KSTR 72
#define MNEG -30000.0f

__global__ __launch_bounds__(256) void flash_mfma_kernel(
    const bf16* __restrict__ qg, const bf16* __restrict__ kg,
    const bf16* __restrict__ vg, bf16* __restrict__ og)
{
    __shared__ bf16 Ks[BT * KSTR];       // K tile [krow][d]
    __shared__ bf16 Vt[BT * KSTR];       // V tile transposed [d][krow]
    __shared__ bf16 Ps[4][16 * KSTR];    // per-wave P [qrow][kcol]

    const int tid  = threadIdx.x;
    const int wave = tid >> 6;
    const int lane = tid & 63;
    const int c    = lane & 15;
    const int quad = lane >> 4;
    const int qt   = blockIdx.x;
    const int bh   = blockIdx.y;
    const size_t hbase = (size_t)bh * S * D;

    // Q fragments for this wave's 16 q-rows (held in registers)
    bf16x8 qf[2];
    {
        const int qrow = qt * BT + wave * 16 + c;
        #pragma unroll
        for (int kc = 0; kc < 2; ++kc)
            qf[kc] = *(const bf16x8*)(qg + hbase + (size_t)qrow * D + kc * 32 + quad * 8);
    }

    f32x4 of[4];
    float m[4], l[4];
    #pragma unroll
    for (int r = 0; r < 4; ++r) {
        m[r] = MNEG; l[r] = 0.f;
        #pragma unroll
        for (int jn = 0; jn < 4; ++jn) of[jn][r] = 0.f;
    }

    for (int kt = 0; kt <= qt; ++kt) {
        __syncthreads();   // prior iteration's frag reads complete
        // ---- stage K tile (row-major, b128 writes) ----
        #pragma unroll
        for (int i = 0; i < 2; ++i) {
            int vi = tid + i * 256;
            int r  = vi >> 3, c0 = (vi & 7) * 8;
            *(bf16x8*)&Ks[r * KSTR + c0] =
                *(const bf16x8*)(kg + hbase + (size_t)(kt * BT + r) * D + c0);
        }
        // ---- stage V transposed: coalesced scalar column reads ----
        {
            const int d  = tid & 63;
            const int rb = (tid >> 6) * 8;
            #pragma unroll
            for (int pass = 0; pass < 2; ++pass) {
                int r0 = rb + pass * 32;
                union { bf16 h[8]; bf16x8 v; } u;
                #pragma unroll
                for (int j = 0; j < 8; ++j)
                    u.h[j] = vg[hbase + (size_t)(kt * BT + r0 + j) * D + d];
                *(bf16x8*)&Vt[d * KSTR + r0] = u.v;
            }
        }
        __syncthreads();

        // ---- S = Q . K^T via MFMA ----
        f32x4 sc[4];
        #pragma unroll
        for (int jn = 0; jn < 4; ++jn) {
            bf16x8 kf0 = *(const bf16x8*)&Ks[(jn * 16 + c) * KSTR + quad * 8];
            bf16x8 kf1 = *(const bf16x8*)&Ks[(jn * 16 + c) * KSTR + 32 + quad * 8];
            f32x4 s = {0.f, 0.f, 0.f, 0.f};
            s = __builtin_amdgcn_mfma_f32_16x16x32_bf16(qf[0], kf0, s, 0, 0, 0);
            s = __builtin_amdgcn_mfma_f32_16x16x32_bf16(qf[1], kf1, s, 0, 0, 0);
            sc[jn] = s;
        }

        // ---- softmax (per accumulator row quad*4+r), P -> LDS (bf16) ----
        float alpha[4];
        #pragma unroll
        for (int r = 0; r < 4; ++r) {
            float s0 = sc[0][r] * 0.125f;
            float s1 = sc[1][r] * 0.125f;
            float s2 = sc[2][r] * 0.125f;
            float s3 = sc[3][r] * 0.125f;
            if (kt == qt) {   // causal mask within diagonal tile
                int qrl = wave * 16 + quad * 4 + r;
                if (c      > qrl) s0 = MNEG;
                if (c + 16 > qrl) s1 = MNEG;
                if (c + 32 > qrl) s2 = MNEG;
                if (c + 48 > qrl) s3 = MNEG;
            }
            float rm = fmaxf(fmaxf(s0, s1), fmaxf(s2, s3));
            #pragma unroll
            for (int off = 8; off > 0; off >>= 1) rm = fmaxf(rm, __shfl_xor(rm, off));
            float mn = fmaxf(m[r], rm);
            alpha[r] = __expf(m[r] - mn);
            float p0 = __expf(s0 - mn), p1 = __expf(s1 - mn);
            float p2 = __expf(s2 - mn), p3 = __expf(s3 - mn);
            float rs = (p0 + p1) + (p2 + p3);
            #pragma unroll
            for (int off = 8; off > 0; off >>= 1) rs += __shfl_xor(rs, off);
            l[r] = l[r] * alpha[r] + rs;
            m[r] = mn;
            bf16* prow = &Ps[wave][(quad * 4 + r) * KSTR + c];
            prow[0]  = __float2bfloat16(p0);
            prow[16] = __float2bfloat16(p1);
            prow[32] = __float2bfloat16(p2);
            prow[48] = __float2bfloat16(p3);
            #pragma unroll
            for (int jn = 0; jn < 4; ++jn) of[jn][r] *= alpha[r];
        }

        // wave-internal LDS visibility for Ps (cross-lane, same wave)
        asm volatile("s_waitcnt lgkmcnt(0)" ::: "memory");

        // ---- O += P . V via MFMA ----
        #pragma unroll
        for (int kc = 0; kc < 2; ++kc) {
            bf16x8 pf = *(const bf16x8*)&Ps[wave][c * KSTR + kc * 32 + quad * 8];
            #pragma unroll
            for (int jn = 0; jn < 4; ++jn) {
                bf16x8 vf = *(const bf16x8*)&Vt[(jn * 16 + c) * KSTR + kc * 32 + quad * 8];
                of[jn] = __builtin_amdgcn_mfma_f32_16x16x32_bf16(pf, vf, of[jn], 0, 0, 0);
            }
        }
    }

    // ---- epilogue: normalize, store bf16 [B][H][S][D] ----
    const int qrow0 = qt * BT + wave * 16 + quad * 4;
    #pragma unroll
    for (int r = 0; r < 4; ++r) {
        float inv = 1.f / l[r];
        size_t base = hbase + (size_t)(qrow0 + r) * D + c;
        og[base]      = __float2bfloat16(of[0][r] * inv);
        og[base + 16] = __float2bfloat16(of[1][r] * inv);
        og[base + 32] = __float2bfloat16(of[2][r] * inv);
        og[base + 48] = __float2bfloat16(of[3][r] * inv);
    }
}

// ---------------------------------------------------------------------------
// Kernel 3: output projection (unchanged from R2).
// ---------------------------------------------------------------------------
__global__ __launch_bounds__(256) void out_proj_kernel(
    const bf16* __restrict__ o, const float* __restrict__ Wo,
    const float* __restrict__ bo, void* __restrict__ out,
    const int* __restrict__ flags)
{
    __shared__ float os[4][HID];
    __shared__ float red[4][4][64];
    const int tid = threadIdx.x;
    const int r0  = blockIdx.x * 4;

    #pragma unroll
    for (int i = 0; i < 16; ++i) {
        int idx = tid + i * 256;
        int rr  = idx >> 10;
        int kk  = idx & 1023;
        int h   = kk >> 6, d = kk & 63;
        int row = r0 + rr;
        int bb  = row >> 11;
        int ss  = row & (S - 1);
        os[rr][kk] = b2f(o[((size_t)(bb * H + h) * S + ss) * D + d]);
    }
    __syncthreads();

    const int n = tid & 63, ch = tid >> 6;
    float acc[4] = {0.f, 0.f, 0.f, 0.f};
    for (int kk = ch * 256; kk < ch * 256 + 256; ++kk) {
        float w = Wo[kk * 64 + n];
        #pragma unroll
        for (int r = 0; r < 4; ++r) acc[r] += os[r][kk] * w;
    }
    #pragma unroll
    for (int r = 0; r < 4; ++r) red[ch][r][n] = acc[r];
    __syncthreads();

    {
        int rr = tid >> 6, nn = tid & 63;
        float sum = red[0][rr][nn] + red[1][rr][nn] + red[2][rr][nn] +
                    red[3][rr][nn] + bo[nn];
        size_t oidx = (size_t)(r0 + rr) * 64 + nn;
        if (flags[0]) ((float*)out)[oidx] = sum;
        else          ((bf16*)out)[oidx]  = __float2bfloat16(sum);
    }
}

// ---------------------------------------------------------------------------
extern "C" void kernel_launch(void* const* d_in, const int* in_sizes, int n_in,
                              void* d_out, int out_size, void* d_ws, size_t ws_size,
                              hipStream_t stream)
{
    char* ws = (char*)d_ws;
    const size_t qkv_bytes = (size_t)B * S * HID * sizeof(bf16);  // 16 MiB each
    bf16* qw = (bf16*)(ws);
    bf16* kw = (bf16*)(ws + qkv_bytes);
    bf16* vw = (bf16*)(ws + 2 * qkv_bytes);
    bf16* ow = (bf16*)(ws + 3 * qkv_bytes);

    float* stage = (float*)(ws + 4 * qkv_bytes);
    float* xf  = stage;
    float* wqf = xf  + (size_t)B * S * D;
    float* bqf = wqf + D * HID;
    float* wkf = bqf + HID;
    float* bkf = wkf + D * HID;
    float* wvf = bkf + HID;
    float* bvf = wvf + D * HID;
    float* wof = bvf + HID;
    float* bof = wof + HID * D;
    int* flags = (int*)(bof + D);

    detect_kernel<<<9, 256, 0, stream>>>(d_in[0], d_in[1], d_in[2], d_in[3],
                                         d_in[4], d_in[5], d_in[6], d_in[7],
                                         d_in[8], flags);

    const int  sizes[9] = {B * S * D, D * HID, HID, D * HID, HID,
                           D * HID, HID, HID * D, D};
    float*     dsts[9]  = {xf, wqf, bqf, wkf, bkf, wvf, bvf, wof, bof};
    for (int i = 0; i < 9; ++i) {
        int blocks = (sizes[i] + 255) / 256;
        convert_kernel<<<blocks, 256, 0, stream>>>(d_in[i], dsts[i], sizes[i],
                                                   flags, i);
    }

    qkv_proj_kernel<<<dim3(B * S / 4), 256, 0, stream>>>(xf, wqf, bqf, wkf, bkf,
                                                         wvf, bvf, qw, kw, vw);
    flash_mfma_kernel<<<dim3(S / BT, B * H), 256, 0, stream>>>(qw, kw, vw, ow);
    out_proj_kernel<<<dim3(B * S / 4), 256, 0, stream>>>(ow, wof, bof, d_out, flags);
}

// Round 4
// 391.949 us; speedup vs baseline: 3.0395x; 1.1924x over previous
//
#include <hip/hip_runtime.h>
#include <hip/hip_bf16.h>

#define B 4
#define S 2048
#define H 16
#define D 64
#define HID 1024

typedef __hip_bfloat16 bf16;
typedef __attribute__((ext_vector_type(8))) short bf16x8;
typedef __attribute__((ext_vector_type(4))) float f32x4;

static __device__ __forceinline__ float b2f(bf16 v) { return __bfloat162float(v); }

static __device__ __forceinline__ float ldf(const float* p, size_t i) { return p[i]; }
static __device__ __forceinline__ float ldf(const bf16* p, size_t i) { return b2f(p[i]); }

// ---------------------------------------------------------------------------
// Kernel 0: dtype detector (proven in R2/R3). flags[i]=1 -> fp32.
// ---------------------------------------------------------------------------
__global__ __launch_bounds__(256) void detect_kernel(
    const void* p0, const void* p1, const void* p2, const void* p3,
    const void* p4, const void* p5, const void* p6, const void* p7,
    const void* p8, int* flags)
{
    __shared__ int cnt;
    const void* ps[9] = {p0, p1, p2, p3, p4, p5, p6, p7, p8};
    const int   ns[9] = {B * S * D, D * HID, HID, D * HID, HID,
                         D * HID, HID, HID * D, D};
    const int i = blockIdx.x;
    const bf16* p = (const bf16*)ps[i];
    int n = ns[i];
    if (n > 2048) n = 2048;
    if (threadIdx.x == 0) cnt = 0;
    __syncthreads();
    int wild = 0;
    for (int t = threadIdx.x; t < n; t += 256) {
        float f = b2f(p[t]);
        if (!(f == f) || fabsf(f) > 1e4f) wild++;
    }
    if (wild) atomicAdd(&cnt, wild);
    __syncthreads();
    if (threadIdx.x == 0) flags[i] = (cnt >= 2) ? 1 : 0;
}

// ---------------------------------------------------------------------------
// Kernel 1: fused QKV projection, 16 rows/block, dtype-templated body.
// x:[B*S,64] @ W{q,k,v}:[64,1024] + b -> Q,K,V in [B][H][S][D] bf16.
// ---------------------------------------------------------------------------
template <typename T>
static __device__ __forceinline__ void qkv_body(
    const T* __restrict__ x,
    const T* __restrict__ Wq, const T* __restrict__ bq,
    const T* __restrict__ Wk, const T* __restrict__ bk,
    const T* __restrict__ Wv, const T* __restrict__ bv,
    bf16* __restrict__ q, bf16* __restrict__ k, bf16* __restrict__ v,
    float xs[16][D])
{
    const int tid = threadIdx.x;
    const int r0  = blockIdx.x * 16;

    #pragma unroll
    for (int i = 0; i < 4; ++i) {
        int idx = tid + i * 256;        // 0..1023
        int rr = idx >> 6, cc = idx & 63;
        xs[rr][cc] = ldf(x, (size_t)(r0 + rr) * D + cc);
    }
    __syncthreads();

    for (int cblk = 0; cblk < 4; ++cblk) {
        const int n = cblk * 256 + tid;
        float aq[16], ak[16], av[16];
        #pragma unroll
        for (int r = 0; r < 16; ++r) { aq[r] = 0.f; ak[r] = 0.f; av[r] = 0.f; }
        for (int d = 0; d < D; ++d) {
            float wqv = ldf(Wq, (size_t)d * HID + n);
            float wkv = ldf(Wk, (size_t)d * HID + n);
            float wvv = ldf(Wv, (size_t)d * HID + n);
            #pragma unroll
            for (int r = 0; r < 16; ++r) {
                float xv = xs[r][d];
                aq[r] += xv * wqv;
                ak[r] += xv * wkv;
                av[r] += xv * wvv;
            }
        }
        const int h = n >> 6, dd = n & 63;
        const float bqv = ldf(bq, n), bkv = ldf(bk, n), bvv = ldf(bv, n);
        #pragma unroll
        for (int r = 0; r < 16; ++r) {
            int row = r0 + r;
            int bb = row >> 11;          // S = 2048
            int ss = row & (S - 1);
            size_t o = ((size_t)(bb * H + h) * S + ss) * D + dd;
            q[o] = __float2bfloat16(aq[r] + bqv);
            k[o] = __float2bfloat16(ak[r] + bkv);
            v[o] = __float2bfloat16(av[r] + bvv);
        }
    }
}

__global__ __launch_bounds__(256) void qkv_proj_kernel(
    const void* x, const void* Wq, const void* bq, const void* Wk,
    const void* bk, const void* Wv, const void* bv,
    bf16* q, bf16* k, bf16* v, const int* flags)
{
    __shared__ float xs[16][D];
    if (flags[0])
        qkv_body<float>((const float*)x, (const float*)Wq, (const float*)bq,
                        (const float*)Wk, (const float*)bk, (const float*)Wv,
                        (const float*)bv, q, k, v, xs);
    else
        qkv_body<bf16>((const bf16*)x, (const bf16*)Wq, (const bf16*)bq,
                       (const bf16*)Wk, (const bf16*)bk, (const bf16*)Wv,
                       (const bf16*)bv, q, k, v, xs);
}

// ---------------------------------------------------------------------------
// Kernel 2: flash causal attention, bf16 MFMA 16x16x32, triangular pairing.
// Grid (NT/2, B*H); block x handles q-tiles x and NT-1-x  -> exactly NT+1
// k-tile iterations per block (uniform). 256 thr = 4 waves, 16 q-rows/wave.
// Layouts (m89/m91/m120-verified):
//   A-frag: A[m=lane&15][k=quad*8+j]  B-frag: B[k=quad*8+j][n=lane&15]
//   C/D:    D[row=quad*4+r][col=lane&15]
// ---------------------------------------------------------------------------
#define BT   64
#define NT   (S / BT)   // 32
#define KSTR 72
#define PSTR 68         // Ps stride: P-write banks = 8*quad + c/2 -> 2-way (free)
#define MNEG -30000.0f

__global__ __launch_bounds__(256) void flash_mfma_kernel(
    const bf16* __restrict__ qg, const bf16* __restrict__ kg,
    const bf16* __restrict__ vg, bf16* __restrict__ og)
{
    __shared__ bf16 Ks[BT * KSTR];       // K tile [krow][d]
    __shared__ bf16 Vt[BT * KSTR];       // V tile transposed [d][krow]
    __shared__ bf16 Ps[4][16 * PSTR];    // per-wave P [qrow][kcol]

    const int tid  = threadIdx.x;
    const int wave = tid >> 6;
    const int lane = tid & 63;
    const int c    = lane & 15;
    const int quad = lane >> 4;
    const int bh   = blockIdx.y;
    const size_t hbase = (size_t)bh * S * D;

    #pragma unroll 1
    for (int phase = 0; phase < 2; ++phase) {
        const int qt = phase ? (NT - 1 - (int)blockIdx.x) : (int)blockIdx.x;

        // Q fragments for this wave's 16 q-rows
        bf16x8 qf[2];
        {
            const int qrow = qt * BT + wave * 16 + c;
            qf[0] = *(const bf16x8*)(qg + hbase + (size_t)qrow * D + quad * 8);
            qf[1] = *(const bf16x8*)(qg + hbase + (size_t)qrow * D + 32 + quad * 8);
        }

        f32x4 of[4];
        float m[4], l[4];
        #pragma unroll
        for (int r = 0; r < 4; ++r) {
            m[r] = MNEG; l[r] = 0.f;
            #pragma unroll
            for (int jn = 0; jn < 4; ++jn) of[jn][r] = 0.f;
        }

        for (int kt = 0; kt <= qt; ++kt) {
            __syncthreads();   // prior iteration's frag reads complete
            // ---- stage K tile (b128 row-major) ----
            #pragma unroll
            for (int i = 0; i < 2; ++i) {
                int vi = tid + i * 256;
                int r  = vi >> 3, c0 = (vi & 7) * 8;
                *(bf16x8*)&Ks[r * KSTR + c0] =
                    *(const bf16x8*)(kg + hbase + (size_t)(kt * BT + r) * D + c0);
            }
            // ---- stage V transposed (coalesced scalar column reads) ----
            {
                const int d  = tid & 63;
                const int rb = (tid >> 6) * 8;
                #pragma unroll
                for (int pass = 0; pass < 2; ++pass) {
                    int r0 = rb + pass * 32;
                    union { bf16 h[8]; bf16x8 v; } u;
                    #pragma unroll
                    for (int j = 0; j < 8; ++j)
                        u.h[j] = vg[hbase + (size_t)(kt * BT + r0 + j) * D + d];
                    *(bf16x8*)&Vt[d * KSTR + r0] = u.v;
                }
            }
            __syncthreads();

            // ---- S = Q . K^T ----
            f32x4 sc[4];
            #pragma unroll
            for (int jn = 0; jn < 4; ++jn) {
                bf16x8 kf0 = *(const bf16x8*)&Ks[(jn * 16 + c) * KSTR + quad * 8];
                bf16x8 kf1 = *(const bf16x8*)&Ks[(jn * 16 + c) * KSTR + 32 + quad * 8];
                f32x4 s = {0.f, 0.f, 0.f, 0.f};
                s = __builtin_amdgcn_mfma_f32_16x16x32_bf16(qf[0], kf0, s, 0, 0, 0);
                s = __builtin_amdgcn_mfma_f32_16x16x32_bf16(qf[1], kf1, s, 0, 0, 0);
                sc[jn] = s;
            }

            // ---- online softmax; P -> LDS (bf16) ----
            float alpha[4];
            #pragma unroll
            for (int r = 0; r < 4; ++r) {
                float s0 = sc[0][r] * 0.125f;
                float s1 = sc[1][r] * 0.125f;
                float s2 = sc[2][r] * 0.125f;
                float s3 = sc[3][r] * 0.125f;
                if (kt == qt) {
                    int qrl = wave * 16 + quad * 4 + r;
                    if (c      > qrl) s0 = MNEG;
                    if (c + 16 > qrl) s1 = MNEG;
                    if (c + 32 > qrl) s2 = MNEG;
                    if (c + 48 > qrl) s3 = MNEG;
                }
                float rm = fmaxf(fmaxf(s0, s1), fmaxf(s2, s3));
                #pragma unroll
                for (int off = 8; off > 0; off >>= 1) rm = fmaxf(rm, __shfl_xor(rm, off));
                float mn = fmaxf(m[r], rm);
                alpha[r] = __expf(m[r] - mn);
                float p0 = __expf(s0 - mn), p1 = __expf(s1 - mn);
                float p2 = __expf(s2 - mn), p3 = __expf(s3 - mn);
                float rs = (p0 + p1) + (p2 + p3);
                #pragma unroll
                for (int off = 8; off > 0; off >>= 1) rs += __shfl_xor(rs, off);
                l[r] = l[r] * alpha[r] + rs;
                m[r] = mn;
                bf16* prow = &Ps[wave][(quad * 4 + r) * PSTR + c];
                prow[0]  = __float2bfloat16(p0);
                prow[16] = __float2bfloat16(p1);
                prow[32] = __float2bfloat16(p2);
                prow[48] = __float2bfloat16(p3);
                #pragma unroll
                for (int jn = 0; jn < 4; ++jn) of[jn][r] *= alpha[r];
            }

            // wave-internal LDS visibility for Ps (cross-lane, same wave)
            asm volatile("s_waitcnt lgkmcnt(0)" ::: "memory");

            // ---- O += P . V ----
            #pragma unroll
            for (int kc = 0; kc < 2; ++kc) {
                bf16x8 pf = *(const bf16x8*)&Ps[wave][c * PSTR + kc * 32 + quad * 8];
                #pragma unroll
                for (int jn = 0; jn < 4; ++jn) {
                    bf16x8 vf = *(const bf16x8*)&Vt[(jn * 16 + c) * KSTR + kc * 32 + quad * 8];
                    of[jn] = __builtin_amdgcn_mfma_f32_16x16x32_bf16(pf, vf, of[jn], 0, 0, 0);
                }
            }
        }

        // ---- epilogue: normalize, store bf16 [B][H][S][D] ----
        const int qrow0 = qt * BT + wave * 16 + quad * 4;
        #pragma unroll
        for (int r = 0; r < 4; ++r) {
            float inv = 1.f / l[r];
            size_t base = hbase + (size_t)(qrow0 + r) * D + c;
            og[base]      = __float2bfloat16(of[0][r] * inv);
            og[base + 16] = __float2bfloat16(of[1][r] * inv);
            og[base + 32] = __float2bfloat16(of[2][r] * inv);
            og[base + 48] = __float2bfloat16(of[3][r] * inv);
        }
    }
}

// ---------------------------------------------------------------------------
// Kernel 3: output projection, 8 rows/block, dtype-templated weights/output.
// ---------------------------------------------------------------------------
template <typename T>
static __device__ __forceinline__ void outproj_body(
    const bf16* __restrict__ o, const T* __restrict__ Wo,
    const T* __restrict__ bo, void* __restrict__ out, int out_fp32,
    float os[8][HID], float red[4][8][64])
{
    const int tid = threadIdx.x;
    const int r0  = blockIdx.x * 8;

    #pragma unroll
    for (int i = 0; i < 32; ++i) {
        int idx = tid + i * 256;        // 0..8191
        int rr  = idx >> 10;
        int kk  = idx & 1023;
        int h   = kk >> 6, d = kk & 63;
        int row = r0 + rr;
        int bb  = row >> 11;
        int ss  = row & (S - 1);
        os[rr][kk] = b2f(o[((size_t)(bb * H + h) * S + ss) * D + d]);
    }
    __syncthreads();

    const int n = tid & 63, ch = tid >> 6;
    float acc[8];
    #pragma unroll
    for (int r = 0; r < 8; ++r) acc[r] = 0.f;
    for (int kk = ch * 256; kk < ch * 256 + 256; ++kk) {
        float w = ldf(Wo, (size_t)kk * 64 + n);
        #pragma unroll
        for (int r = 0; r < 8; ++r) acc[r] += os[r][kk] * w;
    }
    #pragma unroll
    for (int r = 0; r < 8; ++r) red[ch][r][n] = acc[r];
    __syncthreads();

    #pragma unroll
    for (int rsel = 0; rsel < 2; ++rsel) {
        int rr = (tid >> 6) + rsel * 4;
        int nn = tid & 63;
        float sum = red[0][rr][nn] + red[1][rr][nn] + red[2][rr][nn] +
                    red[3][rr][nn] + ldf(bo, nn);
        size_t oidx = (size_t)(r0 + rr) * 64 + nn;
        if (out_fp32) ((float*)out)[oidx] = sum;
        else          ((bf16*)out)[oidx]  = __float2bfloat16(sum);
    }
}

__global__ __launch_bounds__(256) void out_proj_kernel(
    const bf16* o, const void* Wo, const void* bo, void* out,
    const int* flags)
{
    __shared__ float os[8][HID];
    __shared__ float red[4][8][64];
    if (flags[0])
        outproj_body<float>(o, (const float*)Wo, (const float*)bo, out, 1, os, red);
    else
        outproj_body<bf16>(o, (const bf16*)Wo, (const bf16*)bo, out, 0, os, red);
}

// ---------------------------------------------------------------------------
extern "C" void kernel_launch(void* const* d_in, const int* in_sizes, int n_in,
                              void* d_out, int out_size, void* d_ws, size_t ws_size,
                              hipStream_t stream)
{
    char* ws = (char*)d_ws;
    const size_t qkv_bytes = (size_t)B * S * HID * sizeof(bf16);  // 16 MiB each
    bf16* qw = (bf16*)(ws);
    bf16* kw = (bf16*)(ws + qkv_bytes);
    bf16* vw = (bf16*)(ws + 2 * qkv_bytes);
    bf16* ow = (bf16*)(ws + 3 * qkv_bytes);
    int* flags = (int*)(ws + 4 * qkv_bytes);

    detect_kernel<<<9, 256, 0, stream>>>(d_in[0], d_in[1], d_in[2], d_in[3],
                                         d_in[4], d_in[5], d_in[6], d_in[7],
                                         d_in[8], flags);

    qkv_proj_kernel<<<dim3(B * S / 16), 256, 0, stream>>>(
        d_in[0], d_in[1], d_in[2], d_in[3], d_in[4], d_in[5], d_in[6],
        qw, kw, vw, flags);

    flash_mfma_kernel<<<dim3(NT / 2, B * H), 256, 0, stream>>>(qw, kw, vw, ow);

    out_proj_kernel<<<dim3(B * S / 8), 256, 0, stream>>>(ow, d_in[7], d_in[8],
                                                         d_out, flags);
}

// Round 5
// 237.311 us; speedup vs baseline: 5.0201x; 1.6516x over previous
//
#include <hip/hip_runtime.h>
#include <hip/hip_bf16.h>

#define B 4
#define S 2048
#define H 16
#define D 64
#define HID 1024

typedef __hip_bfloat16 bf16;
typedef __attribute__((ext_vector_type(8))) short bf16x8;
typedef __attribute__((ext_vector_type(4))) float f32x4;

static __device__ __forceinline__ float b2f(bf16 v) { return __bfloat162float(v); }
static __device__ __forceinline__ float ldf(const float* p, size_t i) { return p[i]; }
static __device__ __forceinline__ float ldf(const bf16* p, size_t i) { return b2f(p[i]); }

// ---------------------------------------------------------------------------
// Kernel 0: dtype detector (proven R2-R4). flags[i]=1 -> fp32.
// ---------------------------------------------------------------------------
__global__ __launch_bounds__(256) void detect_kernel(
    const void* p0, const void* p1, const void* p2, const void* p3,
    const void* p4, const void* p5, const void* p6, const void* p7,
    const void* p8, int* flags)
{
    __shared__ int cnt;
    const void* ps[9] = {p0, p1, p2, p3, p4, p5, p6, p7, p8};
    const int   ns[9] = {B * S * D, D * HID, HID, D * HID, HID,
                         D * HID, HID, HID * D, D};
    const int i = blockIdx.x;
    const bf16* p = (const bf16*)ps[i];
    int n = ns[i];
    if (n > 2048) n = 2048;
    if (threadIdx.x == 0) cnt = 0;
    __syncthreads();
    int wild = 0;
    for (int t = threadIdx.x; t < n; t += 256) {
        float f = b2f(p[t]);
        if (!(f == f) || fabsf(f) > 1e4f) wild++;
    }
    if (wild) atomicAdd(&cnt, wild);
    __syncthreads();
    if (threadIdx.x == 0) flags[i] = (cnt >= 2) ? 1 : 0;
}

// ---------------------------------------------------------------------------
// Kernel 1: QKV projection as MFMA GEMM.
// Grid (M/128=64, 24): y -> (mat = y>>3, nblk = y&7). Block = 128m x 128n,
// K=64 single shot. Wave w owns rows [w*32, w*32+32).
// Frag discipline (verified in flash): A[m=lane&15][k=quad*8+j] from Xs[m][k];
// B[k][n=lane&15] from Wt[n][k]; C/D [row=quad*4+r][col=lane&15].
// ---------------------------------------------------------------------------
#define QSTR 72

template <typename T>
static __device__ __forceinline__ void qkv_mfma_body(
    const T* __restrict__ x,
    const T* __restrict__ Wq, const T* __restrict__ bq,
    const T* __restrict__ Wk, const T* __restrict__ bk,
    const T* __restrict__ Wv, const T* __restrict__ bv,
    bf16* __restrict__ q, bf16* __restrict__ k, bf16* __restrict__ v,
    bf16* Xs, bf16* Wt, float* bs)
{
    const int tid = threadIdx.x;
    const int mat = blockIdx.y >> 3;
    const int N0  = (blockIdx.y & 7) * 128;
    const int m0  = blockIdx.x * 128;

    const T* W    = (mat == 0) ? Wq : (mat == 1) ? Wk : Wv;
    const T* bias = (mat == 0) ? bq : (mat == 1) ? bk : bv;
    bf16*    dst  = (mat == 0) ? q  : (mat == 1) ? k  : v;

    // ---- stage x tile [128][64] -> Xs (bf16) ----
    #pragma unroll
    for (int i = 0; i < 4; ++i) {
        int item = i * 256 + tid;          // row*8 + oct
        int row = item >> 3, oct = item & 7;
        union { bf16 h[8]; bf16x8 v8; } u;
        #pragma unroll
        for (int j = 0; j < 8; ++j)
            u.h[j] = __float2bfloat16(ldf(x, (size_t)(m0 + row) * D + oct * 8 + j));
        *(bf16x8*)&Xs[row * QSTR + oct * 8] = u.v8;
    }
    // ---- stage W^T tile: Wt[n][k=d], n in [N0,N0+128) ----
    #pragma unroll
    for (int i = 0; i < 4; ++i) {
        int item = i * 256 + tid;          // oct*128 + n
        int n = item & 127, oct = item >> 7;
        union { bf16 h[8]; bf16x8 v8; } u;
        #pragma unroll
        for (int j = 0; j < 8; ++j)
            u.h[j] = __float2bfloat16(ldf(W, (size_t)(oct * 8 + j) * HID + N0 + n));
        *(bf16x8*)&Wt[n * QSTR + oct * 8] = u.v8;
    }
    if (tid < 128) bs[tid] = ldf(bias, N0 + tid);
    __syncthreads();

    const int lane = tid & 63, wave = tid >> 6;
    const int c = lane & 15, quad = lane >> 4;

    bf16x8 af[2][2];
    #pragma unroll
    for (int mg = 0; mg < 2; ++mg)
        #pragma unroll
        for (int kc = 0; kc < 2; ++kc)
            af[mg][kc] = *(const bf16x8*)&Xs[(wave * 32 + mg * 16 + c) * QSTR + kc * 32 + quad * 8];

    f32x4 acc[2][8];
    #pragma unroll
    for (int mg = 0; mg < 2; ++mg)
        #pragma unroll
        for (int ng = 0; ng < 8; ++ng)
            acc[mg][ng] = (f32x4){0.f, 0.f, 0.f, 0.f};

    #pragma unroll
    for (int ng = 0; ng < 8; ++ng) {
        bf16x8 bf0 = *(const bf16x8*)&Wt[(ng * 16 + c) * QSTR + quad * 8];
        bf16x8 bf1 = *(const bf16x8*)&Wt[(ng * 16 + c) * QSTR + 32 + quad * 8];
        #pragma unroll
        for (int mg = 0; mg < 2; ++mg) {
            acc[mg][ng] = __builtin_amdgcn_mfma_f32_16x16x32_bf16(af[mg][0], bf0, acc[mg][ng], 0, 0, 0);
            acc[mg][ng] = __builtin_amdgcn_mfma_f32_16x16x32_bf16(af[mg][1], bf1, acc[mg][ng], 0, 0, 0);
        }
    }

    // ---- epilogue: + bias, store [B][H][S][D] bf16 ----
    #pragma unroll
    for (int ng = 0; ng < 8; ++ng) {
        int n_g = N0 + ng * 16 + c;
        int h = n_g >> 6, dd = n_g & 63;
        float bb_ = bs[ng * 16 + c];
        #pragma unroll
        for (int mg = 0; mg < 2; ++mg) {
            #pragma unroll
            for (int r = 0; r < 4; ++r) {
                int row = m0 + wave * 32 + mg * 16 + quad * 4 + r;
                int b_ = row >> 11, ss = row & (S - 1);
                dst[((size_t)(b_ * H + h) * S + ss) * D + dd] =
                    __float2bfloat16(acc[mg][ng][r] + bb_);
            }
        }
    }
}

__global__ __launch_bounds__(256) void qkv_mfma_kernel(
    const void* x, const void* Wq, const void* bq, const void* Wk,
    const void* bk, const void* Wv, const void* bv,
    bf16* q, bf16* k, bf16* v, const int* flags)
{
    __shared__ bf16 Xs[128 * QSTR];
    __shared__ bf16 Wt[128 * QSTR];
    __shared__ float bs[128];
    if (flags[0])
        qkv_mfma_body<float>((const float*)x, (const float*)Wq, (const float*)bq,
                             (const float*)Wk, (const float*)bk, (const float*)Wv,
                             (const float*)bv, q, k, v, Xs, Wt, bs);
    else
        qkv_mfma_body<bf16>((const bf16*)x, (const bf16*)Wq, (const bf16*)bq,
                            (const bf16*)Wk, (const bf16*)bk, (const bf16*)Wv,
                            (const bf16*)bv, q, k, v, Xs, Wt, bs);
}

// ---------------------------------------------------------------------------
// Kernel 2: flash causal attention (unchanged from R4 except o is now stored
// row-major [B][S][HID] so out_proj can stage it with vector loads).
// ---------------------------------------------------------------------------
#define BT   64
#define NT   (S / BT)   // 32
#define KSTR 72
#define PSTR 68
#define MNEG -30000.0f

__global__ __launch_bounds__(256) void flash_mfma_kernel(
    const bf16* __restrict__ qg, const bf16* __restrict__ kg,
    const bf16* __restrict__ vg, bf16* __restrict__ og)
{
    __shared__ bf16 Ks[BT * KSTR];
    __shared__ bf16 Vt[BT * KSTR];
    __shared__ bf16 Ps[4][16 * PSTR];

    const int tid  = threadIdx.x;
    const int wave = tid >> 6;
    const int lane = tid & 63;
    const int c    = lane & 15;
    const int quad = lane >> 4;
    const int bh   = blockIdx.y;
    const int b_   = bh >> 4, h_ = bh & 15;
    const size_t hbase = (size_t)bh * S * D;

    #pragma unroll 1
    for (int phase = 0; phase < 2; ++phase) {
        const int qt = phase ? (NT - 1 - (int)blockIdx.x) : (int)blockIdx.x;

        bf16x8 qf[2];
        {
            const int qrow = qt * BT + wave * 16 + c;
            qf[0] = *(const bf16x8*)(qg + hbase + (size_t)qrow * D + quad * 8);
            qf[1] = *(const bf16x8*)(qg + hbase + (size_t)qrow * D + 32 + quad * 8);
        }

        f32x4 of[4];
        float m[4], l[4];
        #pragma unroll
        for (int r = 0; r < 4; ++r) {
            m[r] = MNEG; l[r] = 0.f;
            #pragma unroll
            for (int jn = 0; jn < 4; ++jn) of[jn][r] = 0.f;
        }

        for (int kt = 0; kt <= qt; ++kt) {
            __syncthreads();
            #pragma unroll
            for (int i = 0; i < 2; ++i) {
                int vi = tid + i * 256;
                int r  = vi >> 3, c0 = (vi & 7) * 8;
                *(bf16x8*)&Ks[r * KSTR + c0] =
                    *(const bf16x8*)(kg + hbase + (size_t)(kt * BT + r) * D + c0);
            }
            {
                const int d  = tid & 63;
                const int rb = (tid >> 6) * 8;
                #pragma unroll
                for (int pass = 0; pass < 2; ++pass) {
                    int r0 = rb + pass * 32;
                    union { bf16 h[8]; bf16x8 v; } u;
                    #pragma unroll
                    for (int j = 0; j < 8; ++j)
                        u.h[j] = vg[hbase + (size_t)(kt * BT + r0 + j) * D + d];
                    *(bf16x8*)&Vt[d * KSTR + r0] = u.v;
                }
            }
            __syncthreads();

            f32x4 sc[4];
            #pragma unroll
            for (int jn = 0; jn < 4; ++jn) {
                bf16x8 kf0 = *(const bf16x8*)&Ks[(jn * 16 + c) * KSTR + quad * 8];
                bf16x8 kf1 = *(const bf16x8*)&Ks[(jn * 16 + c) * KSTR + 32 + quad * 8];
                f32x4 s = {0.f, 0.f, 0.f, 0.f};
                s = __builtin_amdgcn_mfma_f32_16x16x32_bf16(qf[0], kf0, s, 0, 0, 0);
                s = __builtin_amdgcn_mfma_f32_16x16x32_bf16(qf[1], kf1, s, 0, 0, 0);
                sc[jn] = s;
            }

            float alpha[4];
            #pragma unroll
            for (int r = 0; r < 4; ++r) {
                float s0 = sc[0][r] * 0.125f;
                float s1 = sc[1][r] * 0.125f;
                float s2 = sc[2][r] * 0.125f;
                float s3 = sc[3][r] * 0.125f;
                if (kt == qt) {
                    int qrl = wave * 16 + quad * 4 + r;
                    if (c      > qrl) s0 = MNEG;
                    if (c + 16 > qrl) s1 = MNEG;
                    if (c + 32 > qrl) s2 = MNEG;
                    if (c + 48 > qrl) s3 = MNEG;
                }
                float rm = fmaxf(fmaxf(s0, s1), fmaxf(s2, s3));
                #pragma unroll
                for (int off = 8; off > 0; off >>= 1) rm = fmaxf(rm, __shfl_xor(rm, off));
                float mn = fmaxf(m[r], rm);
                alpha[r] = __expf(m[r] - mn);
                float p0 = __expf(s0 - mn), p1 = __expf(s1 - mn);
                float p2 = __expf(s2 - mn), p3 = __expf(s3 - mn);
                float rs = (p0 + p1) + (p2 + p3);
                #pragma unroll
                for (int off = 8; off > 0; off >>= 1) rs += __shfl_xor(rs, off);
                l[r] = l[r] * alpha[r] + rs;
                m[r] = mn;
                bf16* prow = &Ps[wave][(quad * 4 + r) * PSTR + c];
                prow[0]  = __float2bfloat16(p0);
                prow[16] = __float2bfloat16(p1);
                prow[32] = __float2bfloat16(p2);
                prow[48] = __float2bfloat16(p3);
                #pragma unroll
                for (int jn = 0; jn < 4; ++jn) of[jn][r] *= alpha[r];
            }

            asm volatile("s_waitcnt lgkmcnt(0)" ::: "memory");

            #pragma unroll
            for (int kc = 0; kc < 2; ++kc) {
                bf16x8 pf = *(const bf16x8*)&Ps[wave][c * PSTR + kc * 32 + quad * 8];
                #pragma unroll
                for (int jn = 0; jn < 4; ++jn) {
                    bf16x8 vf = *(const bf16x8*)&Vt[(jn * 16 + c) * KSTR + kc * 32 + quad * 8];
                    of[jn] = __builtin_amdgcn_mfma_f32_16x16x32_bf16(pf, vf, of[jn], 0, 0, 0);
                }
            }
        }

        // ---- epilogue: store o row-major [B][S][HID], hid = h*64 + col ----
        const int s0_ = qt * BT + wave * 16 + quad * 4;
        #pragma unroll
        for (int r = 0; r < 4; ++r) {
            float inv = 1.f / l[r];
            size_t base = ((size_t)(b_ * S + s0_ + r)) * HID + h_ * 64 + c;
            og[base]      = __float2bfloat16(of[0][r] * inv);
            og[base + 16] = __float2bfloat16(of[1][r] * inv);
            og[base + 32] = __float2bfloat16(of[2][r] * inv);
            og[base + 48] = __float2bfloat16(of[3][r] * inv);
        }
    }
}

// ---------------------------------------------------------------------------
// Kernel 3: output projection as MFMA GEMM. o:[8192][1024] @ Wo:[1024][64]+bo.
// Grid 128 blocks x 64 m-rows; wave w owns rows [w*16, w*16+16); K in 16
// chunks of 64 staged to LDS (o vector loads; Wo transposed scalar loads).
// ---------------------------------------------------------------------------
template <typename T>
static __device__ __forceinline__ void outproj_mfma_body(
    const bf16* __restrict__ o, const T* __restrict__ Wo,
    const T* __restrict__ bo, void* __restrict__ out, int out_fp32,
    bf16* Os, bf16* Wot, float* bos)
{
    const int tid = threadIdx.x;
    const int m0  = blockIdx.x * 64;
    const int lane = tid & 63, wave = tid >> 6;
    const int c = lane & 15, quad = lane >> 4;

    if (tid < 64) bos[tid] = ldf(bo, tid);

    f32x4 acc[4];
    #pragma unroll
    for (int ng = 0; ng < 4; ++ng) acc[ng] = (f32x4){0.f, 0.f, 0.f, 0.f};

    for (int chunk = 0; chunk < 16; ++chunk) {
        const int k0 = chunk * 64;
        __syncthreads();   // prior frag reads done (also covers bos, chunk 0)
        // stage o tile [64][64] (vector loads, contiguous)
        #pragma unroll
        for (int i = 0; i < 2; ++i) {
            int item = i * 256 + tid;       // row*8 + oct
            int row = item >> 3, oct = item & 7;
            *(bf16x8*)&Os[row * QSTR + oct * 8] =
                *(const bf16x8*)(o + (size_t)(m0 + row) * HID + k0 + oct * 8);
        }
        // stage Wo^T tile: Wot[n][k], n 0..63
        #pragma unroll
        for (int i = 0; i < 2; ++i) {
            int item = i * 256 + tid;       // oct*64 + n
            int n = item & 63, oct = item >> 6;
            union { bf16 h[8]; bf16x8 v8; } u;
            #pragma unroll
            for (int j = 0; j < 8; ++j)
                u.h[j] = __float2bfloat16(ldf(Wo, (size_t)(k0 + oct * 8 + j) * 64 + n));
            *(bf16x8*)&Wot[n * QSTR + oct * 8] = u.v8;
        }
        __syncthreads();

        bf16x8 a0 = *(const bf16x8*)&Os[(wave * 16 + c) * QSTR + quad * 8];
        bf16x8 a1 = *(const bf16x8*)&Os[(wave * 16 + c) * QSTR + 32 + quad * 8];
        #pragma unroll
        for (int ng = 0; ng < 4; ++ng) {
            bf16x8 b0 = *(const bf16x8*)&Wot[(ng * 16 + c) * QSTR + quad * 8];
            bf16x8 b1 = *(const bf16x8*)&Wot[(ng * 16 + c) * QSTR + 32 + quad * 8];
            acc[ng] = __builtin_amdgcn_mfma_f32_16x16x32_bf16(a0, b0, acc[ng], 0, 0, 0);
            acc[ng] = __builtin_amdgcn_mfma_f32_16x16x32_bf16(a1, b1, acc[ng], 0, 0, 0);
        }
    }

    #pragma unroll
    for (int ng = 0; ng < 4; ++ng) {
        int n = ng * 16 + c;
        float bb_ = bos[n];
        #pragma unroll
        for (int r = 0; r < 4; ++r) {
            int row = m0 + wave * 16 + quad * 4 + r;
            float sum = acc[ng][r] + bb_;
            size_t oidx = (size_t)row * 64 + n;
            if (out_fp32) ((float*)out)[oidx] = sum;
            else          ((bf16*)out)[oidx]  = __float2bfloat16(sum);
        }
    }
}

__global__ __launch_bounds__(256) void out_proj_mfma_kernel(
    const bf16* o, const void* Wo, const void* bo, void* out,
    const int* flags)
{
    __shared__ bf16 Os[64 * QSTR];
    __shared__ bf16 Wot[64 * QSTR];
    __shared__ float bos[64];
    if (flags[0])
        outproj_mfma_body<float>(o, (const float*)Wo, (const float*)bo, out, 1,
                                 Os, Wot, bos);
    else
        outproj_mfma_body<bf16>(o, (const bf16*)Wo, (const bf16*)bo, out, 0,
                                Os, Wot, bos);
}

// ---------------------------------------------------------------------------
extern "C" void kernel_launch(void* const* d_in, const int* in_sizes, int n_in,
                              void* d_out, int out_size, void* d_ws, size_t ws_size,
                              hipStream_t stream)
{
    char* ws = (char*)d_ws;
    const size_t qkv_bytes = (size_t)B * S * HID * sizeof(bf16);  // 16 MiB each
    bf16* qw = (bf16*)(ws);
    bf16* kw = (bf16*)(ws + qkv_bytes);
    bf16* vw = (bf16*)(ws + 2 * qkv_bytes);
    bf16* ow = (bf16*)(ws + 3 * qkv_bytes);
    int* flags = (int*)(ws + 4 * qkv_bytes);

    detect_kernel<<<9, 256, 0, stream>>>(d_in[0], d_in[1], d_in[2], d_in[3],
                                         d_in[4], d_in[5], d_in[6], d_in[7],
                                         d_in[8], flags);

    qkv_mfma_kernel<<<dim3(B * S / 128, 24), 256, 0, stream>>>(
        d_in[0], d_in[1], d_in[2], d_in[3], d_in[4], d_in[5], d_in[6],
        qw, kw, vw, flags);

    flash_mfma_kernel<<<dim3(NT / 2, B * H), 256, 0, stream>>>(qw, kw, vw, ow);

    out_proj_mfma_kernel<<<dim3(B * S / 64), 256, 0, stream>>>(ow, d_in[7],
                                                               d_in[8], d_out,
                                                               flags);
}